// Round 4
// baseline (53.673 us; speedup 1.0000x reference)
//
#include <hip/hip_runtime.h>

#define NBATCH 8
#define HH 256
#define WW 256
#define CC 64
#define HWPTS 65536   // HH*WW
#define NSTEPS_ 50

typedef float vf4 __attribute__((ext_vector_type(4)));

// ---------------------------------------------------------------------------
// Kernel 1: build per-(b,t) affine matrices A (2x3) from theta.
// Output layout (float2-packed, transposed for conflict-free LDS b64 reads):
//   Aout[b*192 + (w*32 + t)*2 + c],  w = 0..2 (x,y,1 coeff), c = 0:vx 1:vy
// ---------------------------------------------------------------------------
__global__ __launch_bounds__(256) void cpab_build_A(const float* __restrict__ theta,
                                                    float* __restrict__ Aout) {
  int tid = threadIdx.x;           // 0..255 == b*32 + t
  int b = tid >> 5, t = tid & 31;
  int cell = t >> 2, k = t & 3;
  int ci = cell & 1, cj = cell >> 1;
  int ll = cj * 3 + ci;
  int lr = ll + 1, ul = ll + 3, ur = ll + 4;
  int cen = 15 + cj * 2 + ci;
  int v0, v1, v2 = cen;
  if (k == 0)      { v0 = ll; v1 = lr; }
  else if (k == 1) { v0 = lr; v1 = ur; }
  else if (k == 2) { v0 = ur; v1 = ul; }
  else             { v0 = ul; v1 = ll; }

  int vs[3] = {v0, v1, v2};
  double xs[3], ys[3];
  float Vx[3], Vy[3];
  for (int q = 0; q < 3; ++q) {
    int v = vs[q];
    if (v < 15) { xs[q] = (double)(v % 3) * 0.5; ys[q] = (double)(v / 3) * 0.25; }
    else { int u = v - 15; xs[q] = ((double)(u & 1) + 0.5) * 0.5;
           ys[q] = ((double)(u >> 1) + 0.5) * 0.25; }
    int s = (v == 4) ? 0 : (v == 7) ? 1 : (v == 10) ? 2 : (v >= 15) ? (v - 12) : -1;
    if (s >= 0) { Vx[q] = theta[b * 22 + 2 * s]; Vy[q] = theta[b * 22 + 2 * s + 1]; }
    else        { Vx[q] = 0.f; Vy[q] = 0.f; }
  }
  double x0 = xs[0], x1 = xs[1], x2 = xs[2];
  double y0 = ys[0], y1 = ys[1], y2 = ys[2];
  double det = x0 * (y1 - y2) - x1 * (y0 - y2) + x2 * (y0 - y1);
  // P = [[x0,x1,x2],[y0,y1,y2],[1,1,1]];  inv = adj^T / det
  double inv[3][3] = {
      {y1 - y2, x2 - x1, x1 * y2 - x2 * y1},
      {y2 - y0, x0 - x2, x2 * y0 - x0 * y2},
      {y0 - y1, x1 - x0, x0 * y1 - x1 * y0}};
  for (int w = 0; w < 3; ++w) {
    float i0 = (float)(inv[0][w] / det);
    float i1 = (float)(inv[1][w] / det);
    float i2 = (float)(inv[2][w] / det);
    float ax = __fadd_rn(__fadd_rn(__fmul_rn(Vx[0], i0), __fmul_rn(Vx[1], i1)),
                         __fmul_rn(Vx[2], i2));
    float ay = __fadd_rn(__fadd_rn(__fmul_rn(Vy[0], i0), __fmul_rn(Vy[1], i1)),
                         __fmul_rn(Vy[2], i2));
    Aout[b * 192 + (w * 32 + t) * 2]     = ax;
    Aout[b * 192 + (w * 32 + t) * 2 + 1] = ay;
  }
}

// ---------------------------------------------------------------------------
// Kernel 2 (fused, pipelined): each block owns 512 points (2 image rows).
// A = pts 0..255, B = pts 256..511. Integrate A; main loop interleaves B's
// 50 Euler steps (VALU chain) with A's gather/blend (memory), 2-deep reg
// double-buffer; epilogue samples B pipelined. Weights precomputed in LDS.
// ---------------------------------------------------------------------------
__global__ __launch_bounds__(256, 4) void cpab_fused(const float* __restrict__ xin,
                                                     const float* __restrict__ Ain,
                                                     float* __restrict__ out) {
  __shared__ float2 sA2[96];
  __shared__ int    sOff[256];
  __shared__ float4 sW[256];

  int tid = threadIdx.x;
  int bid = blockIdx.x;                      // 1024 blocks
  int swz = ((bid & 7) << 7) | (bid >> 3);   // bijective: 1024 = 8 * 128
  int base_pt = swz << 9;                    // 512 points per block
  int b = bid & 7;                           // batch == XCD

  if (tid < 192) ((float*)sA2)[tid] = Ain[b * 192 + tid];
  __syncthreads();

#define ESTEP(px, py) do {                                              \
    float xc_ = fminf(fmaxf(px, 0.f), 1.f) * 2.0f;                      \
    float yc_ = fminf(fmaxf(py, 0.f), 1.f) * 4.0f;                      \
    float cxf_ = fminf(floorf(xc_), 1.0f);                              \
    float cyf_ = fminf(floorf(yc_), 3.0f);                              \
    float xr_ = xc_ - cxf_, yr_ = yc_ - cyf_;                           \
    int tri_ = (yr_ <= xr_) ? ((yr_ <= 1.0f - xr_) ? 0 : 1)             \
                            : ((yr_ <= 1.0f - xr_) ? 3 : 2);            \
    int cid_ = ((((int)cyf_) << 1) + (int)cxf_) * 4 + tri_;             \
    float2 q0_ = sA2[cid_];                                             \
    float2 q1_ = sA2[32 + cid_];                                        \
    float2 q2_ = sA2[64 + cid_];                                        \
    float vx_ = __fadd_rn(__fadd_rn(__fmul_rn(q0_.x, px), __fmul_rn(q1_.x, py)), q2_.x); \
    float vy_ = __fadd_rn(__fadd_rn(__fmul_rn(q0_.y, px), __fmul_rn(q1_.y, py)), q2_.y); \
    px = __fadd_rn(px, __fmul_rn(0.02f, vx_));                          \
    py = __fadd_rn(py, __fmul_rn(0.02f, vy_));                          \
  } while (0)

#define PINIT(hw, px, py) do {                                          \
    int w_ = (hw) & 255, h_ = (hw) >> 8;                                \
    px = (w_ == 255) ? 1.0f : __fmul_rn((float)w_, 1.0f / 255.0f);      \
    py = (h_ == 255) ? 1.0f : __fmul_rn((float)h_, 1.0f / 255.0f);      \
  } while (0)

#define PFINISH(px, py) do {                                            \
    float gx_ = __fmul_rn(fminf(fmaxf(px, 0.f), 1.f), 255.0f);          \
    float gy_ = __fmul_rn(fminf(fmaxf(py, 0.f), 1.f), 255.0f);          \
    int ix_ = min((int)gx_, 254);                                       \
    int iy_ = min((int)gy_, 254);                                       \
    float wx_ = __fadd_rn(gx_, -(float)ix_);                            \
    float wy_ = __fadd_rn(gy_, -(float)iy_);                            \
    sOff[tid] = (iy_ << 8) + ix_;                                       \
    float4 w4_;                                                         \
    w4_.x = (1.f - wx_) * (1.f - wy_);                                  \
    w4_.y = wx_ * (1.f - wy_);                                          \
    w4_.z = (1.f - wx_) * wy_;                                          \
    w4_.w = wx_ * wy_;                                                  \
    sW[tid] = w4_;                                                      \
  } while (0)

#define LOADS(R, L00, L01, L10, L11, W4, DST, OB) do {                  \
    int task_ = ((R) << 8) + tid;                                       \
    int p_ = task_ >> 4;                                                \
    int c0_ = (task_ & 15) << 2;                                        \
    int off_ = sOff[p_];                                                \
    W4 = sW[p_];                                                        \
    const float4* q_ = xb4 + (off_ << 4) + (c0_ >> 2);                  \
    L00 = q_[0];                                                        \
    L01 = q_[16];                                                       \
    L10 = q_[16 * 256];                                                 \
    L11 = q_[16 * 256 + 16];                                            \
    DST = (OB) + (size_t)p_ * CC + c0_;                                 \
  } while (0)

#define BLEND(L00, L01, L10, L11, W4, DST) do {                         \
    vf4 o_;                                                             \
    o_.x = L00.x * W4.x + L01.x * W4.y + L10.x * W4.z + L11.x * W4.w;   \
    o_.y = L00.y * W4.x + L01.y * W4.y + L10.y * W4.z + L11.y * W4.w;   \
    o_.z = L00.z * W4.x + L01.z * W4.y + L10.z * W4.z + L11.z * W4.w;   \
    o_.w = L00.w * W4.x + L01.w * W4.y + L10.w * W4.z + L11.w * W4.w;   \
    __builtin_nontemporal_store(o_, (vf4*)(DST));                       \
  } while (0)

  // ---- integrate A (points base_pt + tid) ----
  float apx, apy;
  PINIT((base_pt + tid) & (HWPTS - 1), apx, apy);
#pragma unroll 1
  for (int s = 0; s < NSTEPS_; ++s) ESTEP(apx, apy);
  PFINISH(apx, apy);
  __syncthreads();

  // ---- init B (points base_pt + 256 + tid) ----
  float bpx, bpy;
  PINIT((base_pt + 256 + tid) & (HWPTS - 1), bpx, bpy);

  const float4* xb4 = (const float4*)(xin + (size_t)b * ((size_t)HWPTS * CC));
  float* obA = out + (size_t)base_pt * CC;
  float* obB = out + (size_t)(base_pt + 256) * CC;

  // ---- main loop: sample A (16 iters, 2-deep pipeline) + 50 B-steps ----
  float4 A00, A01, A10, A11, B00, B01, B10, B11;
  float4 Wa, Wb;
  float *Da, *Db;
  LOADS(0, A00, A01, A10, A11, Wa, Da, obA);
#pragma unroll
  for (int rr = 0; rr < 8; ++rr) {
    const int r = rr * 2;
#pragma unroll
    for (int s = (r * NSTEPS_) >> 4; s < (((r + 1) * NSTEPS_) >> 4); ++s)
      ESTEP(bpx, bpy);
    LOADS(r + 1, B00, B01, B10, B11, Wb, Db, obA);
    BLEND(A00, A01, A10, A11, Wa, Da);
#pragma unroll
    for (int s = ((r + 1) * NSTEPS_) >> 4; s < (((r + 2) * NSTEPS_) >> 4); ++s)
      ESTEP(bpx, bpy);
    if (r + 2 < 16) LOADS(r + 2, A00, A01, A10, A11, Wa, Da, obA);
    BLEND(B00, B01, B10, B11, Wb, Db);
  }

  // ---- publish B point data, then sample B (pipelined) ----
  __syncthreads();            // all A-phase LDS reads complete
  PFINISH(bpx, bpy);
  __syncthreads();

  LOADS(0, A00, A01, A10, A11, Wa, Da, obB);
#pragma unroll
  for (int rr = 0; rr < 8; ++rr) {
    const int r = rr * 2;
    LOADS(r + 1, B00, B01, B10, B11, Wb, Db, obB);
    BLEND(A00, A01, A10, A11, Wa, Da);
    if (r + 2 < 16) LOADS(r + 2, A00, A01, A10, A11, Wa, Da, obB);
    BLEND(B00, B01, B10, B11, Wb, Db);
  }

#undef ESTEP
#undef PINIT
#undef PFINISH
#undef LOADS
#undef BLEND
}

extern "C" void kernel_launch(void* const* d_in, const int* in_sizes, int n_in,
                              void* d_out, int out_size, void* d_ws, size_t ws_size,
                              hipStream_t stream) {
  const float* x     = (const float*)d_in[0];   // (8,256,256,64) f32
  const float* theta = (const float*)d_in[1];   // (8,22) f32
  float* out  = (float*)d_out;                  // (8,256,256,64) f32
  float* Abuf = (float*)d_ws;                   // 8*192 floats = 6 KiB

  cpab_build_A<<<1, 256, 0, stream>>>(theta, Abuf);
  cpab_fused<<<NBATCH * HWPTS / 512, 256, 0, stream>>>(x, Abuf, out);
}

// Round 5
// 44.325 us; speedup vs baseline: 1.2109x; 1.2109x over previous
//
#include <hip/hip_runtime.h>

#define NBATCH 8
#define HH 256
#define WW 256
#define CC 64
#define HWPTS 65536   // HH*WW
#define NSTEPS_ 50

typedef float vf4 __attribute__((ext_vector_type(4)));

// ---------------------------------------------------------------------------
// Kernel 1: build per-(b,t) affine matrices A (2x3) from theta.
// Output layout (float2-packed, transposed for conflict-free LDS b64 reads):
//   Aout[b*192 + (w*32 + t)*2 + c],  w = 0..2 (x,y,1 coeff), c = 0:vx 1:vy
// ---------------------------------------------------------------------------
__global__ __launch_bounds__(256) void cpab_build_A(const float* __restrict__ theta,
                                                    float* __restrict__ Aout) {
  int tid = threadIdx.x;           // 0..255 == b*32 + t
  int b = tid >> 5, t = tid & 31;
  int cell = t >> 2, k = t & 3;
  int ci = cell & 1, cj = cell >> 1;
  int ll = cj * 3 + ci;
  int lr = ll + 1, ul = ll + 3, ur = ll + 4;
  int cen = 15 + cj * 2 + ci;
  int v0, v1, v2 = cen;
  if (k == 0)      { v0 = ll; v1 = lr; }
  else if (k == 1) { v0 = lr; v1 = ur; }
  else if (k == 2) { v0 = ur; v1 = ul; }
  else             { v0 = ul; v1 = ll; }

  int vs[3] = {v0, v1, v2};
  double xs[3], ys[3];
  float Vx[3], Vy[3];
  for (int q = 0; q < 3; ++q) {
    int v = vs[q];
    if (v < 15) { xs[q] = (double)(v % 3) * 0.5; ys[q] = (double)(v / 3) * 0.25; }
    else { int u = v - 15; xs[q] = ((double)(u & 1) + 0.5) * 0.5;
           ys[q] = ((double)(u >> 1) + 0.5) * 0.25; }
    int s = (v == 4) ? 0 : (v == 7) ? 1 : (v == 10) ? 2 : (v >= 15) ? (v - 12) : -1;
    if (s >= 0) { Vx[q] = theta[b * 22 + 2 * s]; Vy[q] = theta[b * 22 + 2 * s + 1]; }
    else        { Vx[q] = 0.f; Vy[q] = 0.f; }
  }
  double x0 = xs[0], x1 = xs[1], x2 = xs[2];
  double y0 = ys[0], y1 = ys[1], y2 = ys[2];
  double det = x0 * (y1 - y2) - x1 * (y0 - y2) + x2 * (y0 - y1);
  // P = [[x0,x1,x2],[y0,y1,y2],[1,1,1]];  inv = adj^T / det
  double inv[3][3] = {
      {y1 - y2, x2 - x1, x1 * y2 - x2 * y1},
      {y2 - y0, x0 - x2, x2 * y0 - x0 * y2},
      {y0 - y1, x1 - x0, x0 * y1 - x1 * y0}};
  for (int w = 0; w < 3; ++w) {
    float i0 = (float)(inv[0][w] / det);
    float i1 = (float)(inv[1][w] / det);
    float i2 = (float)(inv[2][w] / det);
    float ax = __fadd_rn(__fadd_rn(__fmul_rn(Vx[0], i0), __fmul_rn(Vx[1], i1)),
                         __fmul_rn(Vx[2], i2));
    float ay = __fadd_rn(__fadd_rn(__fmul_rn(Vy[0], i0), __fmul_rn(Vy[1], i1)),
                         __fmul_rn(Vy[2], i2));
    Aout[b * 192 + (w * 32 + t) * 2]     = ax;
    Aout[b * 192 + (w * 32 + t) * 2 + 1] = ay;
  }
}

// ---------------------------------------------------------------------------
// Kernel 2: per block: 256 grid points (round-3 structure).
// Phase 1: each thread integrates its point (A float2-packed in LDS,
//   3x ds_read_b64/step); offsets + bilinear weights published to LDS.
// Phase 2: 4 iterations x 4-point groups: 16 float4 gathers issued
//   back-to-back (deep MLP), then 4 blends + nontemporal stores.
// Block swizzle: XCD k <- batch k (L2 row-overlap reuse).
// ---------------------------------------------------------------------------
__global__ __launch_bounds__(256) void cpab_warp_sample(const float* __restrict__ xin,
                                                        const float* __restrict__ Ain,
                                                        float* __restrict__ out) {
  __shared__ float2 sA2[96];
  __shared__ int    sOff[256];
  __shared__ float4 sW[256];

  int tid = threadIdx.x;
  int bid = blockIdx.x;
  int swz = ((bid & 7) << 8) | (bid >> 3);   // bijective: 2048 = 8 * 256
  int base_pt = swz << 8;                    // 256 points per block
  int b = bid & 7;                           // batch == XCD

  if (tid < 192) ((float*)sA2)[tid] = Ain[b * 192 + tid];
  __syncthreads();

  {
    int hw = (base_pt + tid) & (HWPTS - 1);
    int w = hw & 255, h = hw >> 8;
    // np.linspace(0,1,256): i * (1/255) with exact endpoint
    float px = (w == 255) ? 1.0f : __fmul_rn((float)w, 1.0f / 255.0f);
    float py = (h == 255) ? 1.0f : __fmul_rn((float)h, 1.0f / 255.0f);
#pragma unroll 1
    for (int s = 0; s < NSTEPS_; ++s) {
      float xc = fminf(fmaxf(px, 0.f), 1.f) * 2.0f;   // exact (*2)
      float yc = fminf(fmaxf(py, 0.f), 1.f) * 4.0f;   // exact (*4)
      float cxf = fminf(floorf(xc), 1.0f);
      float cyf = fminf(floorf(yc), 3.0f);
      float xr = xc - cxf, yr = yc - cyf;
      int tri = (yr <= xr) ? ((yr <= 1.0f - xr) ? 0 : 1)
                           : ((yr <= 1.0f - xr) ? 3 : 2);
      int cid = ((((int)cyf) << 1) + (int)cxf) * 4 + tri;
      float2 q0 = sA2[cid];        // {a00, a10}
      float2 q1 = sA2[32 + cid];   // {a01, a11}
      float2 q2 = sA2[64 + cid];   // {a02, a12}
      float vx = __fadd_rn(__fadd_rn(__fmul_rn(q0.x, px), __fmul_rn(q1.x, py)), q2.x);
      float vy = __fadd_rn(__fadd_rn(__fmul_rn(q0.y, px), __fmul_rn(q1.y, py)), q2.y);
      px = __fadd_rn(px, __fmul_rn(0.02f, vx));
      py = __fadd_rn(py, __fmul_rn(0.02f, vy));
    }
    float gx = __fmul_rn(fminf(fmaxf(px, 0.f), 1.f), 255.0f);
    float gy = __fmul_rn(fminf(fmaxf(py, 0.f), 1.f), 255.0f);
    int ix = min((int)gx, 254);   // gx >= 0 so (int) == floor
    int iy = min((int)gy, 254);
    float wx = __fadd_rn(gx, -(float)ix);
    float wy = __fadd_rn(gy, -(float)iy);
    sOff[tid] = (iy << 8) + ix;
    float4 w4;
    w4.x = (1.f - wx) * (1.f - wy);
    w4.y = wx * (1.f - wy);
    w4.z = (1.f - wx) * wy;
    w4.w = wx * wy;
    sW[tid] = w4;
  }
  __syncthreads();

  const float4* xb4 = (const float4*)(xin + (size_t)b * ((size_t)HWPTS * CC));
  float* ob = out + (size_t)base_pt * CC;
  int lane_c = tid & 15;     // channel chunk 0..15
  int lane_p = tid >> 4;     // point sub-index 0..15

#pragma unroll
  for (int r = 0; r < 4; ++r) {
    float4 L[4][4];
    float4 W[4];
    const float4* q[4];
#pragma unroll
    for (int g = 0; g < 4; ++g) {
      int p = r * 16 + lane_p + g * 64;
      int off = sOff[p];
      W[g] = sW[p];
      q[g] = xb4 + ((size_t)off << 4) + lane_c;
    }
#pragma unroll
    for (int g = 0; g < 4; ++g) {
      L[g][0] = q[g][0];
      L[g][1] = q[g][16];              // x0+1
      L[g][2] = q[g][16 * 256];        // y0+1
      L[g][3] = q[g][16 * 256 + 16];   // x0+1, y0+1
    }
#pragma unroll
    for (int g = 0; g < 4; ++g) {
      int p = r * 16 + lane_p + g * 64;
      vf4 o;
      o.x = L[g][0].x * W[g].x + L[g][1].x * W[g].y + L[g][2].x * W[g].z + L[g][3].x * W[g].w;
      o.y = L[g][0].y * W[g].x + L[g][1].y * W[g].y + L[g][2].y * W[g].z + L[g][3].y * W[g].w;
      o.z = L[g][0].z * W[g].x + L[g][1].z * W[g].y + L[g][2].z * W[g].z + L[g][3].z * W[g].w;
      o.w = L[g][0].w * W[g].x + L[g][1].w * W[g].y + L[g][2].w * W[g].z + L[g][3].w * W[g].w;
      __builtin_nontemporal_store(o, (vf4*)(ob + (size_t)p * CC + (lane_c << 2)));
    }
  }
}

extern "C" void kernel_launch(void* const* d_in, const int* in_sizes, int n_in,
                              void* d_out, int out_size, void* d_ws, size_t ws_size,
                              hipStream_t stream) {
  const float* x     = (const float*)d_in[0];   // (8,256,256,64) f32
  const float* theta = (const float*)d_in[1];   // (8,22) f32
  float* out  = (float*)d_out;                  // (8,256,256,64) f32
  float* Abuf = (float*)d_ws;                   // 8*192 floats = 6 KiB

  cpab_build_A<<<1, 256, 0, stream>>>(theta, Abuf);
  cpab_warp_sample<<<NBATCH * HWPTS / 256, 256, 0, stream>>>(x, Abuf, out);
}